// Round 1
// baseline (146.890 us; speedup 1.0000x reference)
//
#include <hip/hip_runtime.h>

// Pointer-generator final distribution — fully fused single kernel.
//   Each block owns an 8192-elem tile of one row [row = blockIdx.y,
//   v0 = blockIdx.x*CHUNK]. It:
//     (1) recomputes the row gate p = sigmoid(ctx.w_c + st.w_s + emb.w_y + b)
//         redundantly (10 KB of reads, L2/L3-hit for 3 of 4 tile-blocks;
//         this removes the separate gate kernel's launch + serialization gap,
//         which cost more than the redundant reads),
//     (2) scatters (1-p)*attn into a 32 KB LDS image via ds_add_f32,
//     (3) streams out = p*vocab + lds with nontemporal float4 (no L2 churn
//         from once-touched 131 MB).
//   LDS is EXACTLY 32 KB (5 blocks/CU): the cross-wave gate reduction
//   borrows lds[0..3] before the image is zeroed (2 extra barriers, ~free).
// Roofline: 65.5 MB read + 65.5 MB write ≈ 21 us at the 6.5 TB/s the
// harness's own fill dispatches demonstrate on this buffer.

#define CHUNK 8192   // floats per tile = exactly 32 KB LDS -> 5 blocks/CU

typedef float f4 __attribute__((ext_vector_type(4)));

__global__ __launch_bounds__(256) void pg_fused_kernel(
    const float* __restrict__ vocab_dist,   // [B,V]
    const float* __restrict__ attn_dist,    // [B,T]
    const int*   __restrict__ src_ids,      // [B,T]
    const int*   __restrict__ vocab_size_p, // [1]
    const float* __restrict__ context,      // [B,ENC]
    const float* __restrict__ state,        // [B,HID]
    const float* __restrict__ emb,          // [B,EMB]
    const float* __restrict__ w_c, const float* __restrict__ w_s,
    const float* __restrict__ w_y, const float* __restrict__ bias,
    float* __restrict__ out,                // [B,V]
    int T, int V, int ENC, int HID, int EMB)
{
    __shared__ float lds[CHUNK];            // exactly 32 KB
    const int row = blockIdx.y;
    const int v0  = blockIdx.x * CHUNK;
    const int len = min(CHUNK, V - v0);
    const int tid = threadIdx.x;

    // ---- (1) gate partial dot: acc = sum over this thread's strides ----
    float acc = 0.f;
    {
        const f4* a4 = (const f4*)(context + (size_t)row * ENC);
        const f4* w4 = (const f4*)w_c;
        for (int i = tid; i < (ENC >> 2); i += 256) {
            f4 a = a4[i], w = w4[i];
            acc += a.x * w.x + a.y * w.y + a.z * w.z + a.w * w.w;
        }
    }
    {
        const f4* a4 = (const f4*)(state + (size_t)row * HID);
        const f4* w4 = (const f4*)w_s;
        for (int i = tid; i < (HID >> 2); i += 256) {
            f4 a = a4[i], w = w4[i];
            acc += a.x * w.x + a.y * w.y + a.z * w.z + a.w * w.w;
        }
    }
    {
        const f4* a4 = (const f4*)(emb + (size_t)row * EMB);
        const f4* w4 = (const f4*)w_y;
        for (int i = tid; i < (EMB >> 2); i += 256) {
            f4 a = a4[i], w = w4[i];
            acc += a.x * w.x + a.y * w.y + a.z * w.z + a.w * w.w;
        }
    }
    // wave reduce (64 lanes), then cross-wave via lds[0..3] (pre-zero reuse)
    #pragma unroll
    for (int off = 32; off > 0; off >>= 1)
        acc += __shfl_down(acc, off, 64);
    if ((tid & 63) == 0) lds[tid >> 6] = acc;
    const int vs = *vocab_size_p;           // overlap scalar load with barrier
    __syncthreads();                        // partials visible
    const float s  = lds[0] + lds[1] + lds[2] + lds[3] + bias[0];
    const float p  = 1.f / (1.f + expf(-s));
    const float pc = 1.f - p;
    __syncthreads();                        // all partial-reads done before zero

    // ---- (2) zero the tile image, then scatter copy-contributions ----
    f4* l4 = (f4*)lds;
    #pragma unroll 4
    for (int i = tid; i < (CHUNK >> 2); i += 256)
        l4[i] = (f4){0.f, 0.f, 0.f, 0.f};
    __syncthreads();                        // zeros visible before ds_add

    const float* at = attn_dist + (size_t)row * T;
    const int*   si = src_ids   + (size_t)row * T;
    for (int t = tid; t < T; t += 256) {
        int id = si[t];
        if (id < vs) {
            int off = id - v0;
            if ((unsigned)off < (unsigned)len)
                atomicAdd(&lds[off], pc * at[t]);   // ds_add_f32
        }
    }
    __syncthreads();

    // ---- (3) fused stream: out = p * vocab + lds (nontemporal) ----
    const size_t base = (size_t)row * V + v0;
    const f4* vd4 = (const f4*)(vocab_dist + base);
    f4*       o4  = (f4*)(out + base);
    const int n4 = len >> 2;
    for (int i = tid; i < n4; i += 256) {
        f4 v = __builtin_nontemporal_load(vd4 + i);
        f4 a = l4[i];
        v = v * p + a;
        __builtin_nontemporal_store(v, o4 + i);
    }
    for (int i = (n4 << 2) + tid; i < len; i += 256)   // tail (len % 4)
        out[base + i] = vocab_dist[base + i] * p + lds[i];
}

extern "C" void kernel_launch(void* const* d_in, const int* in_sizes, int n_in,
                              void* d_out, int out_size, void* d_ws, size_t ws_size,
                              hipStream_t stream) {
    const float* vocab_dist = (const float*)d_in[0];
    const float* attn_dist  = (const float*)d_in[1];
    const float* context    = (const float*)d_in[2];
    const float* state      = (const float*)d_in[3];
    const float* emb        = (const float*)d_in[4];
    const int*   src_ids    = (const int*)d_in[5];
    const int*   vocab_sz   = (const int*)d_in[6];
    const float* w_c        = (const float*)d_in[7];
    const float* w_s        = (const float*)d_in[8];
    const float* w_y        = (const float*)d_in[9];
    const float* bias       = (const float*)d_in[10];
    float* out = (float*)d_out;

    const int ENC = in_sizes[7];
    const int HID = in_sizes[8];
    const int EMB = in_sizes[9];
    const int B   = in_sizes[2] / ENC;
    const int T   = in_sizes[1] / B;
    const int V   = in_sizes[0] / B;

    dim3 g((V + CHUNK - 1) / CHUNK, B);
    pg_fused_kernel<<<g, 256, 0, stream>>>(
        vocab_dist, attn_dist, src_ids, vocab_sz,
        context, state, emb, w_c, w_s, w_y, bias,
        out, T, V, ENC, HID, EMB);
}

// Round 3
// 144.405 us; speedup vs baseline: 1.0172x; 1.0172x over previous
//
#include <hip/hip_runtime.h>

// Pointer-generator final distribution, 2-kernel version (R0 structure).
//   k1 gate: p_gen[b] = sigmoid(ctx.w_c + state.w_s + emb.w_y + bias) -> d_ws
//   k2 fused scale+scatter, tiled: each block owns an 8192-elem tile of one
//      row. Scatter (1-p)*attn contributions into a 32KB LDS image of the
//      tile (ds_add_f32 — no global atomics), then stream
//      out = p*vocab + lds in one pass.
// R1 post-mortem: fusing the gate into k2 regressed +7 us (per-block serial
// gate prologue × 2048 blocks + per-XCD redundant HBM fetch of row data).
// R2: infra failure (container acquisition), no data — resubmitting verbatim.
// Single change vs R0: NONTEMPORAL load/store on the 131 MB once-touched
// stream (skip L2 write-allocate thrash). Everything else byte-identical to
// the measured-139.8 baseline.

#define CHUNK 8192   // floats per tile = 32 KB LDS -> 5 blocks/CU max

typedef float f4 __attribute__((ext_vector_type(4)));

__global__ __launch_bounds__(256) void pg_gate_kernel(
    const float* __restrict__ context,  // [B,ENC]
    const float* __restrict__ state,    // [B,HID]
    const float* __restrict__ emb,      // [B,EMB]
    const float* __restrict__ w_c, const float* __restrict__ w_s,
    const float* __restrict__ w_y, const float* __restrict__ bias,
    float* __restrict__ pg,             // [B] out
    int ENC, int HID, int EMB)
{
    const int row = blockIdx.x;
    const int tid = threadIdx.x;
    float acc = 0.f;
    {
        const f4* a4 = (const f4*)(context + (size_t)row * ENC);
        const f4* w4 = (const f4*)w_c;
        for (int i = tid; i < (ENC >> 2); i += 256) {
            f4 a = a4[i], w = w4[i];
            acc += a.x * w.x + a.y * w.y + a.z * w.z + a.w * w.w;
        }
    }
    {
        const f4* a4 = (const f4*)(state + (size_t)row * HID);
        const f4* w4 = (const f4*)w_s;
        for (int i = tid; i < (HID >> 2); i += 256) {
            f4 a = a4[i], w = w4[i];
            acc += a.x * w.x + a.y * w.y + a.z * w.z + a.w * w.w;
        }
    }
    {
        const f4* a4 = (const f4*)(emb + (size_t)row * EMB);
        const f4* w4 = (const f4*)w_y;
        for (int i = tid; i < (EMB >> 2); i += 256) {
            f4 a = a4[i], w = w4[i];
            acc += a.x * w.x + a.y * w.y + a.z * w.z + a.w * w.w;
        }
    }
    #pragma unroll
    for (int off = 32; off > 0; off >>= 1)
        acc += __shfl_down(acc, off, 64);
    __shared__ float red[4];
    if ((tid & 63) == 0) red[tid >> 6] = acc;
    __syncthreads();
    if (tid == 0) {
        float s = red[0] + red[1] + red[2] + red[3] + bias[0];
        pg[row] = 1.f / (1.f + expf(-s));
    }
}

__global__ __launch_bounds__(256) void pg_scale_scatter_kernel(
    const float* __restrict__ vocab_dist,   // [B,V]
    const float* __restrict__ attn_dist,    // [B,T]
    const int*   __restrict__ src_ids,      // [B,T]
    const int*   __restrict__ vocab_size_p, // [1]
    const float* __restrict__ pg,           // [B]
    float* __restrict__ out,                // [B,V]
    int T, int V)
{
    __shared__ float lds[CHUNK];
    const int row = blockIdx.y;
    const int v0  = blockIdx.x * CHUNK;
    const int len = min(CHUNK, V - v0);
    const int tid = threadIdx.x;

    // zero the tile image
    f4* l4 = (f4*)lds;
    #pragma unroll 4
    for (int i = tid; i < (CHUNK >> 2); i += 256)
        l4[i] = (f4){0.f, 0.f, 0.f, 0.f};

    const float p  = pg[row];               // wave-uniform scalar load
    const float pc = 1.f - p;
    const int   vs = *vocab_size_p;
    __syncthreads();                        // zeros visible before ds_add

    // scatter this row's copy-contributions that land in [v0, v0+len)
    const float* at = attn_dist + (size_t)row * T;
    const int*   si = src_ids  + (size_t)row * T;
    for (int t = tid; t < T; t += 256) {
        int id = si[t];
        if (id < vs) {
            int off = id - v0;
            if ((unsigned)off < (unsigned)len)
                atomicAdd(&lds[off], pc * at[t]);   // ds_add_f32
        }
    }
    __syncthreads();

    // fused stream: out = p * vocab + lds  (nontemporal: once-touched 131 MB)
    const size_t base = (size_t)row * V + v0;
    const f4* vd4 = (const f4*)(vocab_dist + base);
    f4*       o4  = (f4*)(out + base);
    const int n4 = len >> 2;
    for (int i = tid; i < n4; i += 256) {
        f4 v = __builtin_nontemporal_load(vd4 + i);
        f4 a = l4[i];
        v.x = v.x * p + a.x;
        v.y = v.y * p + a.y;
        v.z = v.z * p + a.z;
        v.w = v.w * p + a.w;
        __builtin_nontemporal_store(v, o4 + i);
    }
    for (int i = (n4 << 2) + tid; i < len; i += 256)   // tail (len % 4)
        out[base + i] = vocab_dist[base + i] * p + lds[i];
}

extern "C" void kernel_launch(void* const* d_in, const int* in_sizes, int n_in,
                              void* d_out, int out_size, void* d_ws, size_t ws_size,
                              hipStream_t stream) {
    const float* vocab_dist = (const float*)d_in[0];
    const float* attn_dist  = (const float*)d_in[1];
    const float* context    = (const float*)d_in[2];
    const float* state      = (const float*)d_in[3];
    const float* emb        = (const float*)d_in[4];
    const int*   src_ids    = (const int*)d_in[5];
    const int*   vocab_sz   = (const int*)d_in[6];
    const float* w_c        = (const float*)d_in[7];
    const float* w_s        = (const float*)d_in[8];
    const float* w_y        = (const float*)d_in[9];
    const float* bias       = (const float*)d_in[10];
    float* out = (float*)d_out;
    float* pg  = (float*)d_ws;             // [B] floats of scratch

    const int ENC = in_sizes[7];
    const int HID = in_sizes[8];
    const int EMB = in_sizes[9];
    const int B   = in_sizes[2] / ENC;
    const int T   = in_sizes[1] / B;
    const int V   = in_sizes[0] / B;

    pg_gate_kernel<<<B, 256, 0, stream>>>(context, state, emb,
                                          w_c, w_s, w_y, bias, pg,
                                          ENC, HID, EMB);

    dim3 g2((V + CHUNK - 1) / CHUNK, B);
    pg_scale_scatter_kernel<<<g2, 256, 0, stream>>>(
        vocab_dist, attn_dist, src_ids, vocab_sz, pg, out, T, V);
}

// Round 4
// 139.924 us; speedup vs baseline: 1.0498x; 1.0320x over previous
//
#include <hip/hip_runtime.h>

// Pointer-generator final distribution, 2-kernel version (R0 structure —
// the measured-139.8us best).
//   k1 gate: p_gen[b] = sigmoid(ctx.w_c + state.w_s + emb.w_y + bias) -> d_ws
//   k2 fused scale+scatter, tiled: each block owns an 8192-elem tile of one
//      row. Scatter (1-p)*attn contributions into a 32KB LDS image of the
//      tile (ds_add_f32 — no global atomics), then stream
//      out = p*vocab + lds in one pass.
// Experiment ledger (all single-variable vs this baseline):
//   R1 gate-fused single kernel: +7.1us (per-block serial gate prologue x2048
//      blocks; per-XCD redundant HBM refetch of row vectors).
//   R3 nontemporal ld/st on the 131MB stream: +4.6us (nt forfeits L2 sector
//      combining on a pure float4 stream; plain stream already at 81-85% of
//      peak, same as the harness's own fill dispatches on these buffers).
// Conclusion: this structure is the controllable floor — k2 is within a few
// us of its ~21us traffic roofline; the timed window is dominated by harness
// 256MiB poison fills (~41us each at 81-85% HBM peak) we cannot affect.

#define CHUNK 8192   // floats per tile = 32 KB LDS -> 5 blocks/CU max

typedef float f4 __attribute__((ext_vector_type(4)));

__global__ __launch_bounds__(256) void pg_gate_kernel(
    const float* __restrict__ context,  // [B,ENC]
    const float* __restrict__ state,    // [B,HID]
    const float* __restrict__ emb,      // [B,EMB]
    const float* __restrict__ w_c, const float* __restrict__ w_s,
    const float* __restrict__ w_y, const float* __restrict__ bias,
    float* __restrict__ pg,             // [B] out
    int ENC, int HID, int EMB)
{
    const int row = blockIdx.x;
    const int tid = threadIdx.x;
    float acc = 0.f;
    {
        const f4* a4 = (const f4*)(context + (size_t)row * ENC);
        const f4* w4 = (const f4*)w_c;
        for (int i = tid; i < (ENC >> 2); i += 256) {
            f4 a = a4[i], w = w4[i];
            acc += a.x * w.x + a.y * w.y + a.z * w.z + a.w * w.w;
        }
    }
    {
        const f4* a4 = (const f4*)(state + (size_t)row * HID);
        const f4* w4 = (const f4*)w_s;
        for (int i = tid; i < (HID >> 2); i += 256) {
            f4 a = a4[i], w = w4[i];
            acc += a.x * w.x + a.y * w.y + a.z * w.z + a.w * w.w;
        }
    }
    {
        const f4* a4 = (const f4*)(emb + (size_t)row * EMB);
        const f4* w4 = (const f4*)w_y;
        for (int i = tid; i < (EMB >> 2); i += 256) {
            f4 a = a4[i], w = w4[i];
            acc += a.x * w.x + a.y * w.y + a.z * w.z + a.w * w.w;
        }
    }
    #pragma unroll
    for (int off = 32; off > 0; off >>= 1)
        acc += __shfl_down(acc, off, 64);
    __shared__ float red[4];
    if ((tid & 63) == 0) red[tid >> 6] = acc;
    __syncthreads();
    if (tid == 0) {
        float s = red[0] + red[1] + red[2] + red[3] + bias[0];
        pg[row] = 1.f / (1.f + expf(-s));
    }
}

__global__ __launch_bounds__(256) void pg_scale_scatter_kernel(
    const float* __restrict__ vocab_dist,   // [B,V]
    const float* __restrict__ attn_dist,    // [B,T]
    const int*   __restrict__ src_ids,      // [B,T]
    const int*   __restrict__ vocab_size_p, // [1]
    const float* __restrict__ pg,           // [B]
    float* __restrict__ out,                // [B,V]
    int T, int V)
{
    __shared__ float lds[CHUNK];
    const int row = blockIdx.y;
    const int v0  = blockIdx.x * CHUNK;
    const int len = min(CHUNK, V - v0);
    const int tid = threadIdx.x;

    // zero the tile image
    f4* l4 = (f4*)lds;
    #pragma unroll 4
    for (int i = tid; i < (CHUNK >> 2); i += 256)
        l4[i] = (f4){0.f, 0.f, 0.f, 0.f};

    const float p  = pg[row];               // wave-uniform scalar load
    const float pc = 1.f - p;
    const int   vs = *vocab_size_p;
    __syncthreads();                        // zeros visible before ds_add

    // scatter this row's copy-contributions that land in [v0, v0+len)
    const float* at = attn_dist + (size_t)row * T;
    const int*   si = src_ids  + (size_t)row * T;
    for (int t = tid; t < T; t += 256) {
        int id = si[t];
        if (id < vs) {
            int off = id - v0;
            if ((unsigned)off < (unsigned)len)
                atomicAdd(&lds[off], pc * at[t]);   // ds_add_f32
        }
    }
    __syncthreads();

    // fused stream: out = p * vocab + lds
    const size_t base = (size_t)row * V + v0;
    const f4* vd4 = (const f4*)(vocab_dist + base);
    f4*       o4  = (f4*)(out + base);
    const int n4 = len >> 2;
    for (int i = tid; i < n4; i += 256) {
        f4 v = vd4[i];
        f4 a = l4[i];
        v.x = v.x * p + a.x;
        v.y = v.y * p + a.y;
        v.z = v.z * p + a.z;
        v.w = v.w * p + a.w;
        o4[i] = v;
    }
    for (int i = (n4 << 2) + tid; i < len; i += 256)   // tail (len % 4)
        out[base + i] = vocab_dist[base + i] * p + lds[i];
}

extern "C" void kernel_launch(void* const* d_in, const int* in_sizes, int n_in,
                              void* d_out, int out_size, void* d_ws, size_t ws_size,
                              hipStream_t stream) {
    const float* vocab_dist = (const float*)d_in[0];
    const float* attn_dist  = (const float*)d_in[1];
    const float* context    = (const float*)d_in[2];
    const float* state      = (const float*)d_in[3];
    const float* emb        = (const float*)d_in[4];
    const int*   src_ids    = (const int*)d_in[5];
    const int*   vocab_sz   = (const int*)d_in[6];
    const float* w_c        = (const float*)d_in[7];
    const float* w_s        = (const float*)d_in[8];
    const float* w_y        = (const float*)d_in[9];
    const float* bias       = (const float*)d_in[10];
    float* out = (float*)d_out;
    float* pg  = (float*)d_ws;             // [B] floats of scratch

    const int ENC = in_sizes[7];
    const int HID = in_sizes[8];
    const int EMB = in_sizes[9];
    const int B   = in_sizes[2] / ENC;
    const int T   = in_sizes[1] / B;
    const int V   = in_sizes[0] / B;

    pg_gate_kernel<<<B, 256, 0, stream>>>(context, state, emb,
                                          w_c, w_s, w_y, bias, pg,
                                          ENC, HID, EMB);

    dim3 g2((V + CHUNK - 1) / CHUNK, B);
    pg_scale_scatter_kernel<<<g2, 256, 0, stream>>>(
        vocab_dist, attn_dist, src_ids, vocab_sz, pg, out, T, V);
}